// Round 4
// baseline (317.787 us; speedup 1.0000x reference)
//
#include <hip/hip_runtime.h>
#include <stdint.h>

#define EPS 1e-8f

typedef __attribute__((ext_vector_type(8))) __bf16 bf16x8;
typedef __attribute__((ext_vector_type(4))) float f32x4;

static constexpr int BO = 6400;   // B*O
static constexpr int AA = 16;     // attributes
static constexpr int DD = 1024;   // D
static constexpr int HH = 512;    // H

// ---------- helpers ----------
__device__ __forceinline__ unsigned short f2bf(float x) {
    uint32_t b = __float_as_uint(x);
    b += 0x7fffu + ((b >> 16) & 1u);   // round-to-nearest-even (finite inputs)
    return (unsigned short)(b >> 16);
}

__device__ __forceinline__ float fast_tanh(float x) {
    // tanh(x) = 1 - 2/(exp(2x)+1); exp overflow -> inf -> rcp -> 0 -> +1 (correct)
    float e = __expf(2.0f * x);
    return 1.0f - __fdividef(2.0f, e + 1.0f);
}

// ---------- kernel 1: f32 -> bf16 staging of W_obj only ----------
__global__ __launch_bounds__(256) void k_prep_w(const float* __restrict__ W,
                                                unsigned short* __restrict__ W_bf) {
    const int i = blockIdx.x * 256 + threadIdx.x;   // 65536 8-elem units
    const long off = (long)i * 8;
    float4 v0 = *(const float4*)(W + off);
    float4 v1 = *(const float4*)(W + off + 4);
    union { unsigned short u[8]; int4 v; } pk;
    pk.u[0] = f2bf(v0.x); pk.u[1] = f2bf(v0.y); pk.u[2] = f2bf(v0.z); pk.u[3] = f2bf(v0.w);
    pk.u[4] = f2bf(v1.x); pk.u[5] = f2bf(v1.y); pk.u[6] = f2bf(v1.z); pk.u[7] = f2bf(v1.w);
    *(int4*)(W_bf + off) = pk.v;
}

// ---------- kernel 2: att_obj = obj @ W^T + b_obj, f32 out ----------
// 4 waves/block, 64x64 tile, M-split: wave w owns rows [m0+w*16, +16) x all 64 cols.
// acc = 4 f32x4 = 16 VGPR/wave -> ~13 resident waves/CU to hide cold-A HBM latency.
// XCD strip mapping: xcd = b&7 owns a contiguous 13-mt strip (A 3.3 MB + B 1 MB L2-fit).
__global__ __launch_bounds__(256) void k_gemm(const float* __restrict__ obj,            // [6400][1024] f32
                                              const unsigned short* __restrict__ W_bf,  // [512][1024]  bf16
                                              const float* __restrict__ b_obj,          // [512]
                                              float* __restrict__ att_obj) {            // [6400][512]  f32
    const int wv   = threadIdx.x >> 6;
    const int lane = threadIdx.x & 63;
    const int xcd  = blockIdx.x & 7;
    const int j    = blockIdx.x >> 3;        // 0..103
    const int mt   = xcd * 13 + (j % 13);    // 0..103
    if (mt >= 100) return;                   // idle pad blocks
    const int nt   = j / 13;                 // 0..7
    const int m0   = mt * 64 + wv * 16;
    const int n0   = nt * 64;
    const int lr   = lane & 15;
    const int lk   = (lane >> 4) * 8;

    const float*          ap = obj  + (size_t)(m0 + lr) * DD + lk;
    const unsigned short* bp = W_bf + (size_t)(n0 + lr) * DD + lk;

    f32x4 acc[4];
    #pragma unroll
    for (int jj = 0; jj < 4; ++jj) acc[jj] = f32x4{0.f, 0.f, 0.f, 0.f};

    // 2-deep software pipeline: prefetch k+32 while MFMA on k
    float4 a_lo = *(const float4*)(ap);
    float4 a_hi = *(const float4*)(ap + 4);
    bf16x8 bfr[4];
    #pragma unroll
    for (int jj = 0; jj < 4; ++jj) bfr[jj] = *(const bf16x8*)(bp + (size_t)jj * 16 * DD);

    #pragma unroll 1
    for (int k0 = 0; k0 < DD; k0 += 32) {
        const int kn = (k0 + 32 < DD) ? (k0 + 32) : 0;   // clamp: no OOB
        float4 na_lo = *(const float4*)(ap + kn);
        float4 na_hi = *(const float4*)(ap + kn + 4);
        bf16x8 nb[4];
        #pragma unroll
        for (int jj = 0; jj < 4; ++jj) nb[jj] = *(const bf16x8*)(bp + (size_t)jj * 16 * DD + kn);

        bf16x8 afr;
        afr[0] = (__bf16)a_lo.x; afr[1] = (__bf16)a_lo.y;
        afr[2] = (__bf16)a_lo.z; afr[3] = (__bf16)a_lo.w;
        afr[4] = (__bf16)a_hi.x; afr[5] = (__bf16)a_hi.y;
        afr[6] = (__bf16)a_hi.z; afr[7] = (__bf16)a_hi.w;
        #pragma unroll
        for (int jj = 0; jj < 4; ++jj)
            acc[jj] = __builtin_amdgcn_mfma_f32_16x16x32_bf16(afr, bfr[jj], acc[jj], 0, 0, 0);

        a_lo = na_lo; a_hi = na_hi;
        #pragma unroll
        for (int jj = 0; jj < 4; ++jj) bfr[jj] = nb[jj];
    }

    // C/D layout: col = lane&15, row = (lane>>4)*4 + reg
    const int crow = (lane >> 4) * 4;
    #pragma unroll
    for (int jj = 0; jj < 4; ++jj) {
        const int n = n0 + jj * 16 + lr;
        const float bb = b_obj[n];
        #pragma unroll
        for (int r = 0; r < 4; ++r)
            att_obj[(size_t)(m0 + crow + r) * HH + n] = acc[jj][r] + bb;
    }
}

// ---------- kernel 3: fused tanh-score + softmax + masked renorm + pooling ----------
// ONE WAVE PER ROW, no LDS, no barriers.
// DIAGNOSTIC BUILD: body executed twice (opaque-zero defeats CSE) so this dispatch
// exceeds the harness ws-poison fills (~255 us) and surfaces in rocprof top-5 with
// its hbm_gbps / VALUBusy / OccupancyPercent counters. Second pass recomputes and
// overwrites identical values -> deterministic, output unchanged.
__global__ __launch_bounds__(256) void k_attn(const float* __restrict__ att_obj,   // [6400][512] f32
                                              const float* __restrict__ p_attr,    // [6400][16][512]
                                              const int* __restrict__ masks,       // [6400][16]
                                              const float* __restrict__ w_alpha,   // [512]
                                              const float* __restrict__ attr_feats,// [6400][16][1024]
                                              float* __restrict__ out) {           // [6400][1024]
    const int wv    = threadIdx.x >> 6;
    const int lane  = threadIdx.x & 63;
    const int row0  = blockIdx.x * 4 + wv;

    int zero;
    asm volatile("v_mov_b32 %0, 0" : "=v"(zero));   // opaque 0: blocks cross-rep CSE

    #pragma unroll 1
    for (int rep = 0; rep < 2; ++rep) {
        const int row = row0 + rep * zero;

        const f32x4* att4 = (const f32x4*)(att_obj + (size_t)row * HH);
        const f32x4* wa4  = (const f32x4*)w_alpha;
        const f32x4 av0 = att4[lane],      av1 = att4[64 + lane];
        const f32x4 wv0 = wa4[lane],       wv1 = wa4[64 + lane];

        // phase 1: per-attr partial dot over lane's 8 h-values
        const f32x4* p4 = (const f32x4*)(p_attr + (size_t)row * AA * HH);
        float sc[AA];
        #pragma unroll 4
        for (int a = 0; a < AA; ++a) {
            f32x4 x0 = __builtin_nontemporal_load(&p4[a * 128 + lane]);
            f32x4 x1 = __builtin_nontemporal_load(&p4[a * 128 + 64 + lane]);
            float s;
            s  = wv0.x * fast_tanh(x0.x + av0.x);
            s += wv0.y * fast_tanh(x0.y + av0.y);
            s += wv0.z * fast_tanh(x0.z + av0.z);
            s += wv0.w * fast_tanh(x0.w + av0.w);
            s += wv1.x * fast_tanh(x1.x + av1.x);
            s += wv1.y * fast_tanh(x1.y + av1.y);
            s += wv1.z * fast_tanh(x1.z + av1.z);
            s += wv1.w * fast_tanh(x1.w + av1.w);
            sc[a] = s;
        }

        // cross-lane butterfly: every lane ends with all 16 full scores
        #pragma unroll
        for (int d = 1; d < 64; d <<= 1) {
            #pragma unroll
            for (int a = 0; a < AA; ++a) sc[a] += __shfl_xor(sc[a], d);
        }

        // phase 2: softmax + mask + renorm, lane-local (b_alpha cancels)
        const int4* m4 = (const int4*)(masks + (size_t)row * AA);
        float mk[AA];
        {
            int4 m0v = m4[0], m1v = m4[1], m2v = m4[2], m3v = m4[3];
            mk[0]=(float)m0v.x; mk[1]=(float)m0v.y; mk[2]=(float)m0v.z; mk[3]=(float)m0v.w;
            mk[4]=(float)m1v.x; mk[5]=(float)m1v.y; mk[6]=(float)m1v.z; mk[7]=(float)m1v.w;
            mk[8]=(float)m2v.x; mk[9]=(float)m2v.y; mk[10]=(float)m2v.z; mk[11]=(float)m2v.w;
            mk[12]=(float)m3v.x; mk[13]=(float)m3v.y; mk[14]=(float)m3v.z; mk[15]=(float)m3v.w;
        }
        float mx = sc[0];
        #pragma unroll
        for (int a = 1; a < AA; ++a) mx = fmaxf(mx, sc[a]);
        float S = 0.f, T = 0.f;
        #pragma unroll
        for (int a = 0; a < AA; ++a) {
            float e = __expf(sc[a] - mx);
            sc[a] = e * mk[a];
            S += e;
            T += sc[a];
        }
        const float inv = 1.0f / (T + EPS * S);
        #pragma unroll
        for (int a = 0; a < AA; ++a) sc[a] *= inv;

        // phase 3: streaming weighted pooling; lane owns float4 slots {c*64+lane}
        const f32x4* af4 = (const f32x4*)(attr_feats + (size_t)row * AA * DD);
        f32x4 acc0 = {0.f,0.f,0.f,0.f}, acc1 = acc0, acc2 = acc0, acc3 = acc0;
        #pragma unroll 4
        for (int a = 0; a < AA; ++a) {
            f32x4 v0 = __builtin_nontemporal_load(&af4[a * 256 +       lane]);
            f32x4 v1 = __builtin_nontemporal_load(&af4[a * 256 +  64 + lane]);
            f32x4 v2 = __builtin_nontemporal_load(&af4[a * 256 + 128 + lane]);
            f32x4 v3 = __builtin_nontemporal_load(&af4[a * 256 + 192 + lane]);
            const float w = sc[a];
            acc0 += w * v0;
            acc1 += w * v1;
            acc2 += w * v2;
            acc3 += w * v3;
        }
        f32x4* o4 = (f32x4*)(out + (size_t)row * DD);
        __builtin_nontemporal_store(acc0, &o4[      lane]);
        __builtin_nontemporal_store(acc1, &o4[ 64 + lane]);
        __builtin_nontemporal_store(acc2, &o4[128 + lane]);
        __builtin_nontemporal_store(acc3, &o4[192 + lane]);
    }
}

extern "C" void kernel_launch(void* const* d_in, const int* in_sizes, int n_in,
                              void* d_out, int out_size, void* d_ws, size_t ws_size,
                              hipStream_t stream) {
    const float* obj_vecs   = (const float*)d_in[0];
    const float* attr_feats = (const float*)d_in[1];
    const float* p_attr     = (const float*)d_in[2];
    const int*   masks      = (const int*)d_in[3];
    const float* W_obj      = (const float*)d_in[4];
    const float* b_obj      = (const float*)d_in[5];
    const float* w_alpha    = (const float*)d_in[6];
    // d_in[7] = b_alpha: uniform additive shift before softmax -> cancels exactly
    float* out = (float*)d_out;

    char* ws = (char*)d_ws;
    float*          att_obj = (float*)ws;                       // 13,107,200 B
    unsigned short* W_bf    = (unsigned short*)(ws + 13107200); //  1,048,576 B
    // total ws use: 14,155,776 B

    k_prep_w<<<256, 256, 0, stream>>>(W_obj, W_bf);
    k_gemm<<<832, 256, 0, stream>>>(obj_vecs, W_bf, b_obj, att_obj);
    k_attn<<<BO / 4, 256, 0, stream>>>(att_obj, p_attr, masks, w_alpha, attr_feats, out);
}

// Round 5
// 213.539 us; speedup vs baseline: 1.4882x; 1.4882x over previous
//
#include <hip/hip_runtime.h>
#include <stdint.h>

#define EPS 1e-8f

typedef __attribute__((ext_vector_type(8))) __bf16 bf16x8;
typedef __attribute__((ext_vector_type(4))) float f32x4;

static constexpr int BO = 6400;   // B*O
static constexpr int AA = 16;     // attributes
static constexpr int DD = 1024;   // D
static constexpr int HH = 512;    // H

// ---------- helpers ----------
__device__ __forceinline__ unsigned short f2bf(float x) {
    uint32_t b = __float_as_uint(x);
    b += 0x7fffu + ((b >> 16) & 1u);   // round-to-nearest-even (finite inputs)
    return (unsigned short)(b >> 16);
}

__device__ __forceinline__ float fast_tanh(float x) {
    // tanh(x) = 1 - 2/(exp(2x)+1); exp overflow -> inf -> rcp -> 0 -> +1 (correct)
    float e = __expf(2.0f * x);
    return 1.0f - __fdividef(2.0f, e + 1.0f);
}

// ---------- kernel 1: f32 -> bf16 staging of W_obj only ----------
__global__ __launch_bounds__(256) void k_prep_w(const float* __restrict__ W,
                                                unsigned short* __restrict__ W_bf) {
    const int i = blockIdx.x * 256 + threadIdx.x;   // 65536 8-elem units
    const long off = (long)i * 8;
    float4 v0 = *(const float4*)(W + off);
    float4 v1 = *(const float4*)(W + off + 4);
    union { unsigned short u[8]; int4 v; } pk;
    pk.u[0] = f2bf(v0.x); pk.u[1] = f2bf(v0.y); pk.u[2] = f2bf(v0.z); pk.u[3] = f2bf(v0.w);
    pk.u[4] = f2bf(v1.x); pk.u[5] = f2bf(v1.y); pk.u[6] = f2bf(v1.z); pk.u[7] = f2bf(v1.w);
    *(int4*)(W_bf + off) = pk.v;
}

// ---------- kernel 2: att_obj = obj @ W^T + b_obj, f32 out ----------
// 4 waves/block, 64x64 tile, M-split across waves; XCD strip mapping (xcd=b&7 owns
// a contiguous 13-mt strip: A-chunk 3.3 MB f32 + B 1 MB bf16 stay L2-resident).
__global__ __launch_bounds__(256) void k_gemm(const float* __restrict__ obj,            // [6400][1024] f32
                                              const unsigned short* __restrict__ W_bf,  // [512][1024]  bf16
                                              const float* __restrict__ b_obj,          // [512]
                                              float* __restrict__ att_obj) {            // [6400][512]  f32
    const int wv   = threadIdx.x >> 6;
    const int lane = threadIdx.x & 63;
    const int xcd  = blockIdx.x & 7;
    const int j    = blockIdx.x >> 3;        // 0..103
    const int mt   = xcd * 13 + (j % 13);    // 0..103
    if (mt >= 100) return;                   // idle pad blocks
    const int nt   = j / 13;                 // 0..7
    const int m0   = mt * 64 + wv * 16;
    const int n0   = nt * 64;
    const int lr   = lane & 15;
    const int lk   = (lane >> 4) * 8;

    const float*          ap = obj  + (size_t)(m0 + lr) * DD + lk;
    const unsigned short* bp = W_bf + (size_t)(n0 + lr) * DD + lk;

    f32x4 acc[4];
    #pragma unroll
    for (int jj = 0; jj < 4; ++jj) acc[jj] = f32x4{0.f, 0.f, 0.f, 0.f};

    // 2-deep software pipeline: prefetch k+32 while MFMA on k
    float4 a_lo = *(const float4*)(ap);
    float4 a_hi = *(const float4*)(ap + 4);
    bf16x8 bfr[4];
    #pragma unroll
    for (int jj = 0; jj < 4; ++jj) bfr[jj] = *(const bf16x8*)(bp + (size_t)jj * 16 * DD);

    #pragma unroll 1
    for (int k0 = 0; k0 < DD; k0 += 32) {
        const int kn = (k0 + 32 < DD) ? (k0 + 32) : 0;   // clamp: no OOB
        float4 na_lo = *(const float4*)(ap + kn);
        float4 na_hi = *(const float4*)(ap + kn + 4);
        bf16x8 nb[4];
        #pragma unroll
        for (int jj = 0; jj < 4; ++jj) nb[jj] = *(const bf16x8*)(bp + (size_t)jj * 16 * DD + kn);

        bf16x8 afr;
        afr[0] = (__bf16)a_lo.x; afr[1] = (__bf16)a_lo.y;
        afr[2] = (__bf16)a_lo.z; afr[3] = (__bf16)a_lo.w;
        afr[4] = (__bf16)a_hi.x; afr[5] = (__bf16)a_hi.y;
        afr[6] = (__bf16)a_hi.z; afr[7] = (__bf16)a_hi.w;
        #pragma unroll
        for (int jj = 0; jj < 4; ++jj)
            acc[jj] = __builtin_amdgcn_mfma_f32_16x16x32_bf16(afr, bfr[jj], acc[jj], 0, 0, 0);

        a_lo = na_lo; a_hi = na_hi;
        #pragma unroll
        for (int jj = 0; jj < 4; ++jj) bfr[jj] = nb[jj];
    }

    // C/D layout: col = lane&15, row = (lane>>4)*4 + reg
    const int crow = (lane >> 4) * 4;
    #pragma unroll
    for (int jj = 0; jj < 4; ++jj) {
        const int n = n0 + jj * 16 + lr;
        const float bb = b_obj[n];
        #pragma unroll
        for (int r = 0; r < 4; ++r)
            att_obj[(size_t)(m0 + crow + r) * HH + n] = acc[jj][r] + bb;
    }
}

// ---------- kernel 3a: raw scores ----------
// One block per row; each 16-lane group owns one attribute (4 waves x 4 groups = 16).
// Homogeneous stream: 8 coalesced 256B p-loads -> 32 tanh -> 4-step group reduce ->
// one 4B score store. No barriers, no butterfly, no softmax. att_obj/w_alpha slices
// are reused by all 4 waves on the same CU (L1-hot) and across blocks (L2-hot).
__global__ __launch_bounds__(256) void k_score(const float* __restrict__ att_obj,  // [6400][512] f32
                                               const float* __restrict__ p_attr,   // [6400][16][512]
                                               const float* __restrict__ w_alpha,  // [512]
                                               float* __restrict__ scores) {       // [6400][16] raw
    const int row = blockIdx.x;
    const int wv  = threadIdx.x >> 6;
    const int lane = threadIdx.x & 63;
    const int grp = lane >> 4;
    const int lg  = lane & 15;
    const int a   = wv * 4 + grp;

    const f32x4* p4  = (const f32x4*)(p_attr + ((size_t)row * AA + a) * HH);
    const f32x4* at4 = (const f32x4*)(att_obj + (size_t)row * HH);
    const f32x4* w4  = (const f32x4*)w_alpha;

    float s = 0.f;
    #pragma unroll
    for (int it = 0; it < 8; ++it) {
        f32x4 pv = __builtin_nontemporal_load(&p4[it * 16 + lg]);
        f32x4 av = at4[it * 16 + lg];
        f32x4 wvv = w4[it * 16 + lg];
        s += wvv.x * fast_tanh(pv.x + av.x);
        s += wvv.y * fast_tanh(pv.y + av.y);
        s += wvv.z * fast_tanh(pv.z + av.z);
        s += wvv.w * fast_tanh(pv.w + av.w);
    }
    // reduce across the 16-lane group (xor of bits 0..3 stays inside the group)
    s += __shfl_xor(s, 1);
    s += __shfl_xor(s, 2);
    s += __shfl_xor(s, 4);
    s += __shfl_xor(s, 8);
    if (lg == 0) scores[(size_t)row * AA + a] = s;
}

// ---------- kernel 3b: softmax + masked renorm + pooling ----------
// One wave per row, 4 rows per block. Tiny lane-local head (broadcast loads of the
// 16 raw scores + masks, ~200 cyc), then a pure 68 KB/row stream. b_alpha cancels.
__global__ __launch_bounds__(256) void k_pool(const float* __restrict__ scores,     // [6400][16] raw
                                              const int* __restrict__ masks,        // [6400][16]
                                              const float* __restrict__ attr_feats, // [6400][16][1024]
                                              float* __restrict__ out) {            // [6400][1024]
    const int wv   = threadIdx.x >> 6;
    const int lane = threadIdx.x & 63;
    const int row  = blockIdx.x * 4 + wv;

    // broadcast loads: all lanes read the same 16 scores / 16 masks
    const f32x4* s4 = (const f32x4*)(scores + (size_t)row * AA);
    const int4*  m4 = (const int4*)(masks + (size_t)row * AA);
    float sc[AA];
    {
        f32x4 v0 = s4[0], v1 = s4[1], v2 = s4[2], v3 = s4[3];
        sc[0]=v0.x; sc[1]=v0.y; sc[2]=v0.z; sc[3]=v0.w;
        sc[4]=v1.x; sc[5]=v1.y; sc[6]=v1.z; sc[7]=v1.w;
        sc[8]=v2.x; sc[9]=v2.y; sc[10]=v2.z; sc[11]=v2.w;
        sc[12]=v3.x; sc[13]=v3.y; sc[14]=v3.z; sc[15]=v3.w;
    }
    float mk[AA];
    {
        int4 m0v = m4[0], m1v = m4[1], m2v = m4[2], m3v = m4[3];
        mk[0]=(float)m0v.x; mk[1]=(float)m0v.y; mk[2]=(float)m0v.z; mk[3]=(float)m0v.w;
        mk[4]=(float)m1v.x; mk[5]=(float)m1v.y; mk[6]=(float)m1v.z; mk[7]=(float)m1v.w;
        mk[8]=(float)m2v.x; mk[9]=(float)m2v.y; mk[10]=(float)m2v.z; mk[11]=(float)m2v.w;
        mk[12]=(float)m3v.x; mk[13]=(float)m3v.y; mk[14]=(float)m3v.z; mk[15]=(float)m3v.w;
    }
    float mx = sc[0];
    #pragma unroll
    for (int a = 1; a < AA; ++a) mx = fmaxf(mx, sc[a]);
    float S = 0.f, T = 0.f;
    #pragma unroll
    for (int a = 0; a < AA; ++a) {
        float e = __expf(sc[a] - mx);
        sc[a] = e * mk[a];
        S += e;
        T += sc[a];
    }
    const float inv = 1.0f / (T + EPS * S);
    #pragma unroll
    for (int a = 0; a < AA; ++a) sc[a] *= inv;

    // streaming weighted pooling; lane owns float4 slots {c*64+lane}
    const f32x4* af4 = (const f32x4*)(attr_feats + (size_t)row * AA * DD);
    f32x4 acc0 = {0.f,0.f,0.f,0.f}, acc1 = acc0, acc2 = acc0, acc3 = acc0;
    #pragma unroll 4
    for (int a = 0; a < AA; ++a) {
        f32x4 v0 = __builtin_nontemporal_load(&af4[a * 256 +       lane]);
        f32x4 v1 = __builtin_nontemporal_load(&af4[a * 256 +  64 + lane]);
        f32x4 v2 = __builtin_nontemporal_load(&af4[a * 256 + 128 + lane]);
        f32x4 v3 = __builtin_nontemporal_load(&af4[a * 256 + 192 + lane]);
        const float w = sc[a];
        acc0 += w * v0;
        acc1 += w * v1;
        acc2 += w * v2;
        acc3 += w * v3;
    }
    f32x4* o4 = (f32x4*)(out + (size_t)row * DD);
    __builtin_nontemporal_store(acc0, &o4[      lane]);
    __builtin_nontemporal_store(acc1, &o4[ 64 + lane]);
    __builtin_nontemporal_store(acc2, &o4[128 + lane]);
    __builtin_nontemporal_store(acc3, &o4[192 + lane]);
}

extern "C" void kernel_launch(void* const* d_in, const int* in_sizes, int n_in,
                              void* d_out, int out_size, void* d_ws, size_t ws_size,
                              hipStream_t stream) {
    const float* obj_vecs   = (const float*)d_in[0];
    const float* attr_feats = (const float*)d_in[1];
    const float* p_attr     = (const float*)d_in[2];
    const int*   masks      = (const int*)d_in[3];
    const float* W_obj      = (const float*)d_in[4];
    const float* b_obj      = (const float*)d_in[5];
    const float* w_alpha    = (const float*)d_in[6];
    // d_in[7] = b_alpha: uniform additive shift before softmax -> cancels exactly
    float* out = (float*)d_out;

    char* ws = (char*)d_ws;
    float*          att_obj = (float*)ws;                                  // 13,107,200 B
    unsigned short* W_bf    = (unsigned short*)(ws + 13107200);            //  1,048,576 B
    float*          scores  = (float*)(ws + 13107200 + 1048576);           //    409,600 B
    // total ws use: 14,565,376 B

    k_prep_w<<<256, 256, 0, stream>>>(W_obj, W_bf);
    k_gemm<<<832, 256, 0, stream>>>(obj_vecs, W_bf, b_obj, att_obj);
    k_score<<<BO, 256, 0, stream>>>(att_obj, p_attr, w_alpha, scores);
    k_pool<<<BO / 4, 256, 0, stream>>>(scores, masks, attr_feats, out);
}

// Round 6
// 178.033 us; speedup vs baseline: 1.7850x; 1.1994x over previous
//
#include <hip/hip_runtime.h>
#include <stdint.h>

#define EPS 1e-8f

typedef __attribute__((ext_vector_type(8))) __bf16 bf16x8;
typedef __attribute__((ext_vector_type(4))) float f32x4;

static constexpr int BO = 6400;   // B*O
static constexpr int AA = 16;     // attributes
static constexpr int DD = 1024;   // D
static constexpr int HH = 512;    // H

// ---------- helpers ----------
__device__ __forceinline__ unsigned short f2bf(float x) {
    uint32_t b = __float_as_uint(x);
    b += 0x7fffu + ((b >> 16) & 1u);   // round-to-nearest-even (finite inputs)
    return (unsigned short)(b >> 16);
}

__device__ __forceinline__ float fast_tanh(float x) {
    // tanh(x) = 1 - 2/(exp(2x)+1); exp overflow -> inf -> rcp -> 0 -> +1 (correct)
    float e = __expf(2.0f * x);
    return 1.0f - __fdividef(2.0f, e + 1.0f);
}

// ---------- kernel 1: f32 -> bf16 staging of W_obj only ----------
__global__ __launch_bounds__(256) void k_prep_w(const float* __restrict__ W,
                                                unsigned short* __restrict__ W_bf) {
    const int i = blockIdx.x * 256 + threadIdx.x;   // 65536 8-elem units
    const long off = (long)i * 8;
    float4 v0 = *(const float4*)(W + off);
    float4 v1 = *(const float4*)(W + off + 4);
    union { unsigned short u[8]; int4 v; } pk;
    pk.u[0] = f2bf(v0.x); pk.u[1] = f2bf(v0.y); pk.u[2] = f2bf(v0.z); pk.u[3] = f2bf(v0.w);
    pk.u[4] = f2bf(v1.x); pk.u[5] = f2bf(v1.y); pk.u[6] = f2bf(v1.z); pk.u[7] = f2bf(v1.w);
    *(int4*)(W_bf + off) = pk.v;
}

// ---------- kernel 2: att_obj = obj @ W^T + b_obj, f32 out ----------
// 4 waves/block, 64x64 tile, M-split across waves; XCD strip mapping (xcd=b&7 owns
// a contiguous 13-mt strip: A-chunk 3.3 MB f32 + B 1 MB bf16 stay L2-resident).
__global__ __launch_bounds__(256) void k_gemm(const float* __restrict__ obj,            // [6400][1024] f32
                                              const unsigned short* __restrict__ W_bf,  // [512][1024]  bf16
                                              const float* __restrict__ b_obj,          // [512]
                                              float* __restrict__ att_obj) {            // [6400][512]  f32
    const int wv   = threadIdx.x >> 6;
    const int lane = threadIdx.x & 63;
    const int xcd  = blockIdx.x & 7;
    const int j    = blockIdx.x >> 3;        // 0..103
    const int mt   = xcd * 13 + (j % 13);    // 0..103
    if (mt >= 100) return;                   // idle pad blocks
    const int nt   = j / 13;                 // 0..7
    const int m0   = mt * 64 + wv * 16;
    const int n0   = nt * 64;
    const int lr   = lane & 15;
    const int lk   = (lane >> 4) * 8;

    const float*          ap = obj  + (size_t)(m0 + lr) * DD + lk;
    const unsigned short* bp = W_bf + (size_t)(n0 + lr) * DD + lk;

    f32x4 acc[4];
    #pragma unroll
    for (int jj = 0; jj < 4; ++jj) acc[jj] = f32x4{0.f, 0.f, 0.f, 0.f};

    // 2-deep software pipeline: prefetch k+32 while MFMA on k
    float4 a_lo = *(const float4*)(ap);
    float4 a_hi = *(const float4*)(ap + 4);
    bf16x8 bfr[4];
    #pragma unroll
    for (int jj = 0; jj < 4; ++jj) bfr[jj] = *(const bf16x8*)(bp + (size_t)jj * 16 * DD);

    #pragma unroll 1
    for (int k0 = 0; k0 < DD; k0 += 32) {
        const int kn = (k0 + 32 < DD) ? (k0 + 32) : 0;   // clamp: no OOB
        float4 na_lo = *(const float4*)(ap + kn);
        float4 na_hi = *(const float4*)(ap + kn + 4);
        bf16x8 nb[4];
        #pragma unroll
        for (int jj = 0; jj < 4; ++jj) nb[jj] = *(const bf16x8*)(bp + (size_t)jj * 16 * DD + kn);

        bf16x8 afr;
        afr[0] = (__bf16)a_lo.x; afr[1] = (__bf16)a_lo.y;
        afr[2] = (__bf16)a_lo.z; afr[3] = (__bf16)a_lo.w;
        afr[4] = (__bf16)a_hi.x; afr[5] = (__bf16)a_hi.y;
        afr[6] = (__bf16)a_hi.z; afr[7] = (__bf16)a_hi.w;
        #pragma unroll
        for (int jj = 0; jj < 4; ++jj)
            acc[jj] = __builtin_amdgcn_mfma_f32_16x16x32_bf16(afr, bfr[jj], acc[jj], 0, 0, 0);

        a_lo = na_lo; a_hi = na_hi;
        #pragma unroll
        for (int jj = 0; jj < 4; ++jj) bfr[jj] = nb[jj];
    }

    // C/D layout: col = lane&15, row = (lane>>4)*4 + reg
    const int crow = (lane >> 4) * 4;
    #pragma unroll
    for (int jj = 0; jj < 4; ++jj) {
        const int n = n0 + jj * 16 + lr;
        const float bb = b_obj[n];
        #pragma unroll
        for (int r = 0; r < 4; ++r)
            att_obj[(size_t)(m0 + crow + r) * HH + n] = acc[jj][r] + bb;
    }
}

// ---------- kernel 3: fused tanh-score + softmax + masked renorm + pooling ----------
// ONE WAVE PER ROW, 4 rows/block, no LDS, no barriers.
// MASK-SKIP: masked attrs (weight == 0 exactly) contribute 0*finite = 0, and their
// scores only enter via EPS*S (<=2e-7 relative) and the softmax max-shift (cancels).
// So skip their p_attr AND attr_feats loads entirely. Mask bits are identical across
// the wave's lanes -> all branches are wave-uniform (no divergence), ~halving traffic.
__global__ __launch_bounds__(256) void k_attn(const float* __restrict__ att_obj,   // [6400][512] f32
                                              const float* __restrict__ p_attr,    // [6400][16][512]
                                              const int* __restrict__ masks,       // [6400][16]
                                              const float* __restrict__ w_alpha,   // [512]
                                              const float* __restrict__ attr_feats,// [6400][16][1024]
                                              float* __restrict__ out) {           // [6400][1024]
    const int wv   = threadIdx.x >> 6;
    const int lane = threadIdx.x & 63;
    const int row  = blockIdx.x * 4 + wv;

    // masks first -> pack into a bitmask (values are 0/1)
    const int4* m4 = (const int4*)(masks + (size_t)row * AA);
    int mbits;
    {
        int4 a = m4[0], b = m4[1], c = m4[2], d = m4[3];
        mbits =  (a.x)       | (a.y << 1)  | (a.z << 2)  | (a.w << 3)
              | (b.x << 4)  | (b.y << 5)  | (b.z << 6)  | (b.w << 7)
              | (c.x << 8)  | (c.y << 9)  | (c.z << 10) | (c.w << 11)
              | (d.x << 12) | (d.y << 13) | (d.z << 14) | (d.w << 15);
    }

    // per-lane att_obj / w_alpha slices (w_alpha L2-hot)
    const f32x4* att4 = (const f32x4*)(att_obj + (size_t)row * HH);
    const f32x4* wa4  = (const f32x4*)w_alpha;
    const f32x4 av0 = att4[lane],      av1 = att4[64 + lane];
    const f32x4 wv0 = wa4[lane],       wv1 = wa4[64 + lane];

    // phase 1: per-attr partial dot, unmasked attrs only
    const f32x4* p4 = (const f32x4*)(p_attr + (size_t)row * AA * HH);
    float sc[AA];
    #pragma unroll
    for (int a = 0; a < AA; ++a) {
        if (mbits & (1 << a)) {     // wave-uniform
            f32x4 x0 = p4[a * 128 + lane];
            f32x4 x1 = p4[a * 128 + 64 + lane];
            float s;
            s  = wv0.x * fast_tanh(x0.x + av0.x);
            s += wv0.y * fast_tanh(x0.y + av0.y);
            s += wv0.z * fast_tanh(x0.z + av0.z);
            s += wv0.w * fast_tanh(x0.w + av0.w);
            s += wv1.x * fast_tanh(x1.x + av1.x);
            s += wv1.y * fast_tanh(x1.y + av1.y);
            s += wv1.z * fast_tanh(x1.z + av1.z);
            s += wv1.w * fast_tanh(x1.w + av1.w);
            sc[a] = s;
        } else {
            sc[a] = 0.f;
        }
    }

    // cross-lane butterfly (unmasked attrs only): every lane gets full scores
    #pragma unroll
    for (int d = 1; d < 64; d <<= 1) {
        #pragma unroll
        for (int a = 0; a < AA; ++a)
            if (mbits & (1 << a)) sc[a] += __shfl_xor(sc[a], d);
    }

    // phase 2: softmax over unmasked + renorm, lane-local (b_alpha cancels).
    // With masked e == 0, S == T, so denominator = T*(1+EPS); guard all-masked.
    float mx = -3.0e38f;
    #pragma unroll
    for (int a = 0; a < AA; ++a)
        if (mbits & (1 << a)) mx = fmaxf(mx, sc[a]);
    float T = 0.f;
    float wgt[AA];
    #pragma unroll
    for (int a = 0; a < AA; ++a) {
        float e = (mbits & (1 << a)) ? __expf(sc[a] - mx) : 0.f;
        wgt[a] = e;
        T += e;
    }
    const float inv = (T > 0.f) ? 1.0f / (T * (1.0f + EPS)) : 0.f;
    #pragma unroll
    for (int a = 0; a < AA; ++a) wgt[a] *= inv;

    // phase 3: streaming weighted pooling, skipping zero-weight attrs.
    // lane owns float4 slots {c*64+lane}, 4 KB per attr row, fully coalesced.
    const f32x4* af4 = (const f32x4*)(attr_feats + (size_t)row * AA * DD);
    f32x4 acc0 = {0.f,0.f,0.f,0.f}, acc1 = acc0, acc2 = acc0, acc3 = acc0;
    #pragma unroll
    for (int a = 0; a < AA; ++a) {
        if (wgt[a] > 0.f) {         // wave-uniform (same wgt vector on all lanes)
            f32x4 v0 = af4[a * 256 +       lane];
            f32x4 v1 = af4[a * 256 +  64 + lane];
            f32x4 v2 = af4[a * 256 + 128 + lane];
            f32x4 v3 = af4[a * 256 + 192 + lane];
            const float w = wgt[a];
            acc0 += w * v0;
            acc1 += w * v1;
            acc2 += w * v2;
            acc3 += w * v3;
        }
    }
    f32x4* o4 = (f32x4*)(out + (size_t)row * DD);
    o4[      lane] = acc0;
    o4[ 64 + lane] = acc1;
    o4[128 + lane] = acc2;
    o4[192 + lane] = acc3;
}

extern "C" void kernel_launch(void* const* d_in, const int* in_sizes, int n_in,
                              void* d_out, int out_size, void* d_ws, size_t ws_size,
                              hipStream_t stream) {
    const float* obj_vecs   = (const float*)d_in[0];
    const float* attr_feats = (const float*)d_in[1];
    const float* p_attr     = (const float*)d_in[2];
    const int*   masks      = (const int*)d_in[3];
    const float* W_obj      = (const float*)d_in[4];
    const float* b_obj      = (const float*)d_in[5];
    const float* w_alpha    = (const float*)d_in[6];
    // d_in[7] = b_alpha: uniform additive shift before softmax -> cancels exactly
    float* out = (float*)d_out;

    char* ws = (char*)d_ws;
    float*          att_obj = (float*)ws;                       // 13,107,200 B
    unsigned short* W_bf    = (unsigned short*)(ws + 13107200); //  1,048,576 B
    // total ws use: 14,155,776 B

    k_prep_w<<<256, 256, 0, stream>>>(W_obj, W_bf);
    k_gemm<<<832, 256, 0, stream>>>(obj_vecs, W_bf, b_obj, att_obj);
    k_attn<<<BO / 4, 256, 0, stream>>>(att_obj, p_attr, masks, w_alpha, attr_feats, out);
}